// Round 3
// baseline (348.543 us; speedup 1.0000x reference)
//
#include <hip/hip_runtime.h>
#include <math.h>

typedef __attribute__((ext_vector_type(8))) short bf16x8;
typedef __attribute__((ext_vector_type(4))) float f32x4;
typedef unsigned short u16;
typedef unsigned int u32;

#define DEVFN static __device__ __forceinline__

constexpr int NB  = 32;
constexpr int DLn = 290;
constexpr int PLc = 1000;
constexpr int MD  = NB * DLn;   // 9280
constexpr int MP  = NB * PLc;   // 32000

DEVFN u16 f2b(float f) {
    u32 u = __builtin_bit_cast(u32, f);
    u32 r = u + 0x7fffu + ((u >> 16) & 1u);
    return (u16)(r >> 16);
}
DEVFN float b2f(u16 s) { return __builtin_bit_cast(float, (u32)s << 16); }
DEVFN float sigm(float x) { return 1.0f / (1.0f + __expf(-x)); }
DEVFN u32 cvtpk(float lo, float hi) {      // packed f32x2 -> bf16x2 (RNE), 1 instr
    u32 r;
    asm("v_cvt_pk_bf16_f32 %0, %1, %2" : "=v"(r) : "v"(lo), "v"(hi));
    return r;
}

// ---------------- PE table ----------------
__global__ void pe_kernel(float* __restrict__ pe) {
    int p = blockIdx.x, c = threadIdx.x;
    float div = __expf((float)(c & ~1) * (-9.210340371976184f / 256.0f));
    float ang = (float)p * div;
    pe[p * 256 + c] = (c & 1) ? cosf(ang) : sinf(ang);
}

// ---------------- e = x + scale*pe (bf16), 4 cols/thread ----------------
__global__ __launch_bounds__(256) void eadd_kernel(
        const float* __restrict__ drug, const float* __restrict__ prot,
        const float* __restrict__ scale_d, const float* __restrict__ scale_p,
        const float* __restrict__ pe,
        u16* __restrict__ e_d, u16* __restrict__ e_p) {
    int idx = blockIdx.x * 256 + threadIdx.x;
    int r = idx >> 6, c4 = (idx & 63) * 4;
    if (r < MD) {
        int i = r % DLn;
        float s = scale_d[0];
        float4 dv = *(const float4*)&drug[(size_t)r * 256 + c4];
        float4 pv = *(const float4*)&pe[i * 256 + c4];
        u32 a = cvtpk(dv.x + s * pv.x, dv.y + s * pv.y);
        u32 b = cvtpk(dv.z + s * pv.z, dv.w + s * pv.w);
        *(uint2*)&e_d[(size_t)r * 256 + c4] = make_uint2(a, b);
    } else {
        int rr = r - MD;
        int j = rr % PLc;
        float s = scale_p[0];
        float4 dv = *(const float4*)&prot[(size_t)rr * 256 + c4];
        float4 pv = *(const float4*)&pe[j * 256 + c4];
        u32 a = cvtpk(dv.x + s * pv.x, dv.y + s * pv.y);
        u32 b = cvtpk(dv.z + s * pv.z, dv.w + s * pv.w);
        *(uint2*)&e_p[(size_t)rr * 256 + c4] = make_uint2(a, b);
    }
}

// ---------------- weight prep: WT[n][k] bf16, LDS transpose ----------------
struct WPtrs { const float* w[10]; };
__global__ __launch_bounds__(256) void wprep_kernel(WPtrs wp, u16* __restrict__ wt) {
    __shared__ u16 t[64][66];
    int m = blockIdx.y, tile = blockIdx.x;
    int k0 = (tile >> 2) * 64, n0 = (tile & 3) * 64;
    const float* w = wp.w[m];
    int r = threadIdx.x >> 6, c = threadIdx.x & 63;
    #pragma unroll
    for (int q = 0; q < 16; q++) {
        int rr = r + q * 4;
        t[rr][c] = f2b(w[(size_t)(k0 + rr) * 256 + n0 + c]);
    }
    __syncthreads();
    #pragma unroll
    for (int q = 0; q < 16; q++) {
        int rr = r + q * 4;
        wt[((size_t)m << 16) + (size_t)(n0 + rr) * 256 + k0 + c] = t[c][rr];
    }
}

// ---------------- GEMM: C[M,256] = A[M,256] @ WT^T + bias, BK=256 one phase ----------------
struct GCfg { const u16* A; const u16* BT; const float* bias; u16* C; int mtiles; int sig; };
struct GCfg8 { GCfg c[8]; };

__global__ __launch_bounds__(256) void gemm_kernel(GCfg8 cfgs) {
    const GCfg cfg = cfgs.c[blockIdx.z];
    const int mt = blockIdx.x;
    if (mt >= cfg.mtiles) return;
    const int nt = blockIdx.y;
    __shared__ u16 As[64][266];
    __shared__ u16 Bs[64][266];
    const int tid = threadIdx.x;
    const int lane = tid & 63, w = tid >> 6, ln = lane & 15, g = lane >> 4;
    const int lr = tid >> 2, lc = tid & 3;
    const u16* Ag = cfg.A + (size_t)(mt * 64 + lr) * 256 + lc * 8;
    const u16* Bg = cfg.BT + (size_t)(nt * 64 + lr) * 256 + lc * 8;
    uint4 av[8], bv[8];
    #pragma unroll
    for (int kk = 0; kk < 8; kk++) {
        av[kk] = *(const uint4*)(Ag + kk * 32);
        bv[kk] = *(const uint4*)(Bg + kk * 32);
    }
    #pragma unroll
    for (int kk = 0; kk < 8; kk++) {
        *(uint4*)&As[lr][lc * 8 + kk * 32] = av[kk];
        *(uint4*)&Bs[lr][lc * 8 + kk * 32] = bv[kk];
    }
    __syncthreads();
    const int m0 = (w >> 1) * 32, n0 = (w & 1) * 32;
    f32x4 acc[2][2] = {};
    #pragma unroll
    for (int k0 = 0; k0 < 8; k0++) {
        #pragma unroll
        for (int mi = 0; mi < 2; mi++) {
            bf16x8 af = *(const bf16x8*)&As[m0 + mi * 16 + ln][k0 * 32 + g * 8];
            #pragma unroll
            for (int ni = 0; ni < 2; ni++) {
                bf16x8 bfv = *(const bf16x8*)&Bs[n0 + ni * 16 + ln][k0 * 32 + g * 8];
                acc[mi][ni] = __builtin_amdgcn_mfma_f32_16x16x32_bf16(af, bfv, acc[mi][ni], 0, 0, 0);
            }
        }
    }
    #pragma unroll
    for (int mi = 0; mi < 2; mi++) {
        #pragma unroll
        for (int ni = 0; ni < 2; ni++) {
            const int n = nt * 64 + n0 + ni * 16 + ln;
            const float bb = cfg.bias[n];
            const int rowb = mt * 64 + m0 + mi * 16 + g * 4;
            #pragma unroll
            for (int r = 0; r < 4; r++) {
                float v = acc[mi][ni][r] + bb;
                if (cfg.sig) v = sigm(v);
                cfg.C[(size_t)(rowb + r) * 256 + n] = f2b(v);
            }
        }
    }
}

// ---------------- attention: one block per (b,h), no-max softmax, 2 sweeps ----------------
// LDS strides chosen dword-odd (74 u16 = 37 dw, 330 u16 = 165 dw) to kill bank conflicts.
__global__ __launch_bounds__(512) void attn_kernel(
        const u16* __restrict__ Qd, const u16* __restrict__ Kd, const u16* __restrict__ Vd,
        const u16* __restrict__ Kp, const u16* __restrict__ Vp, const u16* __restrict__ Qp,
        const float* __restrict__ alpha,
        u16* __restrict__ ctx_d, u16* __restrict__ ctx_p, float* __restrict__ cm) {
    __shared__ u16 Ks[2][64][74];                     // K' = [Kp;Qp] tiles, dbuf
    __shared__ union {
        struct { u16 VpT[2][32][74]; u16 Pm[320][74]; } s1;   // sweep1
        struct { u16 PT[64][330]; u16 VdT[32][330]; } s2;     // sweep2
    } U;
    __shared__ float r_l[320];
    __shared__ float colpart[8][64];

    const int bh = blockIdx.x, b = bh >> 3, h = bh & 7;
    const int tid = threadIdx.x;
    const int w = tid >> 6, lane = tid & 63, ln = lane & 15, g = lane >> 4;

    const float a = sigm(alpha[0]);
    const float inv = 0.1767766952966369f;
    const float sa = a * inv, sb = (1.0f - a) * inv;
    const int nmt = (w < 4) ? 3 : 2;
    const int mtsA[3] = { w, w + 8, w + 16 };

    const size_t rbd = (size_t)b * DLn * 256 + h * 32;
    const size_t rbp = (size_t)b * PLc * 256 + h * 32;

    // ---- Q' fragments in registers (scaled, masked) ----
    bf16x8 Qf[3][2];
    #pragma unroll
    for (int t = 0; t < 3; t++) {
        const int i = mtsA[t] * 16 + ln;
        #pragma unroll
        for (int ks = 0; ks < 2; ks++) {
            u16 o[8] = {0,0,0,0,0,0,0,0};
            if (t < nmt && i < DLn) {
                const u16* src = (ks ? Kd : Qd) + rbd + (size_t)i * 256 + g * 8;
                const float s = ks ? sb : sa;
                uint4 v = *(const uint4*)src;
                u16 e[8]; *(uint4*)e = v;
                #pragma unroll
                for (int q = 0; q < 8; q++) o[q] = f2b(b2f(e[q]) * s);
            }
            Qf[t][ks] = *(bf16x8*)o;
        }
    }

    // staging thread mappings
    const int s_jj = tid >> 3, s_ch = tid & 7;
    const u16* s_src = ((s_ch >> 2) ? Qp : Kp) + rbp + (s_ch & 3) * 8;
    const int v_j = tid & 63, v_d0 = (tid >> 6) * 4;

    // ---- prologue: stage tile 0 ----
    {
        int j = s_jj;
        uint4 kv = (j < PLc) ? *(const uint4*)(s_src + (size_t)j * 256) : make_uint4(0,0,0,0);
        uint2 vv = (v_j < PLc) ? *(const uint2*)(Vp + rbp + (size_t)v_j * 256 + v_d0) : make_uint2(0,0);
        *(uint4*)&Ks[0][s_jj][s_ch * 8] = kv;
        u16 e[4]; *(uint2*)e = vv;
        #pragma unroll
        for (int q = 0; q < 4; q++) U.s1.VpT[0][v_d0 + q][v_j] = e[q];
    }
    __syncthreads();

    // ---- sweep 1: S^T orientation -> rowsums + ctx_d~ ----
    // j>=PLc stays UNMASKED: S=0 there (zero-staged K'), exp(0)=1 adds exactly 24
    // per row sum (corrected below); padded P values multiply zero-staged Vp.
    float rs[3] = {0.f, 0.f, 0.f};
    f32x4 accd[3][2] = {};
    for (int jt = 0; jt < 16; jt++) {
        const int cur = jt & 1, j0 = jt * 64;
        const int jn = j0 + 64 + s_jj;
        uint4 kv = (jn < PLc) ? *(const uint4*)(s_src + (size_t)jn * 256) : make_uint4(0,0,0,0);
        const int vn = j0 + 64 + v_j;
        uint2 vv = (vn < PLc) ? *(const uint2*)(Vp + rbp + (size_t)vn * 256 + v_d0) : make_uint2(0,0);

        bf16x8 kf[4][2];
        #pragma unroll
        for (int js = 0; js < 4; js++)
            #pragma unroll
            for (int ks = 0; ks < 2; ks++)
                kf[js][ks] = *(const bf16x8*)&Ks[cur][js * 16 + ln][ks * 32 + g * 8];

        #pragma unroll
        for (int t = 0; t < 3; t++) {
            if (t >= nmt) break;
            const int mt = mtsA[t];
            f32x4 acc[4] = {};
            #pragma unroll
            for (int ks = 0; ks < 2; ks++)
                #pragma unroll
                for (int js = 0; js < 4; js++)
                    acc[js] = __builtin_amdgcn_mfma_f32_16x16x32_bf16(kf[js][ks], Qf[t][ks], acc[js], 0, 0, 0);
            const int irow = mt * 16 + ln;
            #pragma unroll
            for (int js = 0; js < 4; js++) {
                float p0 = __expf(acc[js][0]);
                float p1 = __expf(acc[js][1]);
                float p2 = __expf(acc[js][2]);
                float p3 = __expf(acc[js][3]);
                rs[t] += (p0 + p1) + (p2 + p3);
                u32 lo = cvtpk(p0, p1), hi = cvtpk(p2, p3);
                *(uint2*)&U.s1.Pm[irow][js * 16 + g * 4] = make_uint2(lo, hi);
            }
        }
        // ctx_d accumulate (wave-local Pm rows)
        #pragma unroll
        for (int t = 0; t < 3; t++) {
            if (t >= nmt) break;
            const int mt = mtsA[t];
            #pragma unroll
            for (int ks2 = 0; ks2 < 2; ks2++) {
                bf16x8 af = *(const bf16x8*)&U.s1.Pm[mt * 16 + ln][ks2 * 32 + g * 8];
                #pragma unroll
                for (int nd = 0; nd < 2; nd++) {
                    bf16x8 bv = *(const bf16x8*)&U.s1.VpT[cur][nd * 16 + ln][ks2 * 32 + g * 8];
                    accd[t][nd] = __builtin_amdgcn_mfma_f32_16x16x32_bf16(af, bv, accd[t][nd], 0, 0, 0);
                }
            }
        }
        *(uint4*)&Ks[cur ^ 1][s_jj][s_ch * 8] = kv;
        {
            u16 e[4]; *(uint2*)e = vv;
            #pragma unroll
            for (int q = 0; q < 4; q++) U.s1.VpT[cur ^ 1][v_d0 + q][v_j] = e[q];
        }
        __syncthreads();
    }

    // ---- row sums -> reciprocals (subtract the 24 pad-j contributions) ----
    #pragma unroll
    for (int t = 0; t < 3; t++) {
        float v = rs[t];
        v += __shfl_xor(v, 16);
        v += __shfl_xor(v, 32);
        rs[t] = v;
    }
    if (g == 0) {
        #pragma unroll
        for (int t = 0; t < 3; t++) {
            if (t >= nmt) break;
            const int i = mtsA[t] * 16 + ln;
            r_l[i] = (i < DLn) ? 1.0f / (rs[t] - 24.0f) : 0.0f;
        }
    }
    __syncthreads();

    // ---- ctx_d write (scaled), VdTn build, stage Ks tile0 ----
    #pragma unroll
    for (int t = 0; t < 3; t++) {
        if (t >= nmt) break;
        const int mt = mtsA[t];
        #pragma unroll
        for (int r = 0; r < 4; r++) {
            const int i = mt * 16 + g * 4 + r;
            if (i < DLn) {
                const float ri = r_l[i];
                #pragma unroll
                for (int nd = 0; nd < 2; nd++)
                    ctx_d[rbd + (size_t)i * 256 + nd * 16 + ln] = f2b(accd[t][nd][r] * ri);
            }
        }
    }
    for (int c = tid; c < 320 * 8; c += 512) {
        const int i = c >> 3, d0 = (c & 7) * 4;
        u16 o[4] = {0,0,0,0};
        if (i < DLn) {
            const float ri = r_l[i];
            uint2 v = *(const uint2*)(Vd + rbd + (size_t)i * 256 + d0);
            u16 e[4]; *(uint2*)e = v;
            #pragma unroll
            for (int q = 0; q < 4; q++) o[q] = f2b(b2f(e[q]) * ri);
        }
        #pragma unroll
        for (int q = 0; q < 4; q++) U.s2.VdT[d0 + q][i] = o[q];
    }
    {
        int j = s_jj;
        uint4 kv = (j < PLc) ? *(const uint4*)(s_src + (size_t)j * 256) : make_uint4(0,0,0,0);
        *(uint4*)&Ks[0][s_jj][s_ch * 8] = kv;
    }
    float rr[3][4];
    #pragma unroll
    for (int t = 0; t < 3; t++)
        #pragma unroll
        for (int r = 0; r < 4; r++)
            rr[t][r] = (t < nmt) ? r_l[mtsA[t] * 16 + g * 4 + r] : 0.0f;
    __syncthreads();

    // ---- sweep 2: S orientation -> ctx_p + column means ----
    for (int jt = 0; jt < 16; jt++) {
        const int cur = jt & 1, j0 = jt * 64;
        const int jn = j0 + 64 + s_jj;
        uint4 kv = (jn < PLc) ? *(const uint4*)(s_src + (size_t)jn * 256) : make_uint4(0,0,0,0);

        bf16x8 kf[4][2];
        #pragma unroll
        for (int js = 0; js < 4; js++)
            #pragma unroll
            for (int ks = 0; ks < 2; ks++)
                kf[js][ks] = *(const bf16x8*)&Ks[cur][js * 16 + ln][ks * 32 + g * 8];

        float csl[4] = {0.f, 0.f, 0.f, 0.f};
        #pragma unroll
        for (int t = 0; t < 3; t++) {
            if (t >= nmt) break;
            const int mt = mtsA[t];
            f32x4 acc[4] = {};
            #pragma unroll
            for (int ks = 0; ks < 2; ks++)
                #pragma unroll
                for (int js = 0; js < 4; js++)
                    acc[js] = __builtin_amdgcn_mfma_f32_16x16x32_bf16(Qf[t][ks], kf[js][ks], acc[js], 0, 0, 0);
            #pragma unroll
            for (int js = 0; js < 4; js++) {
                float p0 = __expf(acc[js][0]);
                float p1 = __expf(acc[js][1]);
                float p2 = __expf(acc[js][2]);
                float p3 = __expf(acc[js][3]);
                csl[js] += p0 * rr[t][0] + p1 * rr[t][1] + p2 * rr[t][2] + p3 * rr[t][3];
                u32 lo = cvtpk(p0, p1), hi = cvtpk(p2, p3);
                *(uint2*)&U.s2.PT[js * 16 + ln][mt * 16 + g * 4] = make_uint2(lo, hi);
            }
        }
        #pragma unroll
        for (int js = 0; js < 4; js++) {
            float v = csl[js];
            v += __shfl_xor(v, 16);
            v += __shfl_xor(v, 32);
            csl[js] = v;
        }
        if (g == 0) {
            #pragma unroll
            for (int js = 0; js < 4; js++) colpart[w][js * 16 + ln] = csl[js];
        }
        *(uint4*)&Ks[cur ^ 1][s_jj][s_ch * 8] = kv;
        __syncthreads();

        // phase 2: ctx_p tile (all 8 waves) + cm (wave 0)
        {
            const int js2 = w & 3, ds2 = w >> 2;
            f32x4 ap = {};
            #pragma unroll
            for (int k = 0; k < 10; k++) {
                bf16x8 af = *(const bf16x8*)&U.s2.PT[js2 * 16 + ln][k * 32 + g * 8];
                bf16x8 bv = *(const bf16x8*)&U.s2.VdT[ds2 * 16 + ln][k * 32 + g * 8];
                ap = __builtin_amdgcn_mfma_f32_16x16x32_bf16(af, bv, ap, 0, 0, 0);
            }
            const int d = ds2 * 16 + ln;
            #pragma unroll
            for (int r = 0; r < 4; r++) {
                const int j = j0 + js2 * 16 + g * 4 + r;
                if (j < PLc) ctx_p[rbp + (size_t)j * 256 + d] = f2b(ap[r]);
            }
        }
        if (w == 0) {
            float tot = 0.f;
            #pragma unroll
            for (int ww = 0; ww < 8; ww++) tot += colpart[ww][lane];
            const int j = j0 + lane;
            if (j < PLc) cm[(size_t)(b * PLc + j) * 8 + h] = tot * (1.0f / 290.0f);
        }
        __syncthreads();
    }
}

// ---------------- final combine, 4 cols/thread ----------------
__global__ __launch_bounds__(256) void combine_kernel(
        const float* __restrict__ drug, const float* __restrict__ prot,
        const float* __restrict__ scale_d, const float* __restrict__ scale_p,
        const float* __restrict__ pe,
        const u16* __restrict__ Xd, const u16* __restrict__ Xp,
        const u16* __restrict__ gate_d, const u16* __restrict__ gate_p,
        const float* __restrict__ cm,
        const float* __restrict__ w_fc_dp, const float* __restrict__ b_fc_dp,
        const float* __restrict__ w_fc_pd, const float* __restrict__ b_fc_pd,
        float* __restrict__ out) {
    int idx = blockIdx.x * 256 + threadIdx.x;
    int r = idx >> 6, c4 = (idx & 63) * 4;
    if (r < MD) {
        int b = r / DLn, i = r % DLn;
        float s = scale_d[0];
        float4 dv = *(const float4*)&drug[(size_t)r * 256 + c4];
        float4 pv = *(const float4*)&pe[i * 256 + c4];
        uint2 xv = *(const uint2*)&Xd[(size_t)r * 256 + c4];
        uint2 gv = *(const uint2*)&gate_d[(size_t)r * 256 + c4];
        float4 bb = *(const float4*)&b_fc_dp[c4];
        float da[4] = { bb.x, bb.y, bb.z, bb.w };
        #pragma unroll
        for (int hh = 0; hh < 8; hh++) {
            float4 wv = *(const float4*)&w_fc_dp[hh * 256 + c4];
            da[0] += 0.001f * wv.x; da[1] += 0.001f * wv.y;
            da[2] += 0.001f * wv.z; da[3] += 0.001f * wv.w;
        }
        u16 xe[4]; *(uint2*)xe = xv;
        u16 ge[4]; *(uint2*)ge = gv;
        float e0 = dv.x + s * pv.x, e1 = dv.y + s * pv.y;
        float e2 = dv.z + s * pv.z, e3 = dv.w + s * pv.w;
        float4 o;
        o.x = e0 + b2f(xe[0]) * b2f(ge[0]) * sigm(da[0]);
        o.y = e1 + b2f(xe[1]) * b2f(ge[1]) * sigm(da[1]);
        o.z = e2 + b2f(xe[2]) * b2f(ge[2]) * sigm(da[2]);
        o.w = e3 + b2f(xe[3]) * b2f(ge[3]) * sigm(da[3]);
        *(float4*)&out[((size_t)b * 1290 + i) * 256 + c4] = o;
    } else {
        int rr = r - MD;
        int b = rr / PLc, j = rr % PLc;
        float s = scale_p[0];
        float4 dv = *(const float4*)&prot[(size_t)rr * 256 + c4];
        float4 pv = *(const float4*)&pe[j * 256 + c4];
        uint2 xv = *(const uint2*)&Xp[(size_t)rr * 256 + c4];
        uint2 gv = *(const uint2*)&gate_p[(size_t)rr * 256 + c4];
        float4 bb = *(const float4*)&b_fc_pd[c4];
        float pa[4] = { bb.x, bb.y, bb.z, bb.w };
        #pragma unroll
        for (int hh = 0; hh < 8; hh++) {
            float cmh = cm[(size_t)rr * 8 + hh];
            float4 wv = *(const float4*)&w_fc_pd[hh * 256 + c4];
            pa[0] += cmh * wv.x; pa[1] += cmh * wv.y;
            pa[2] += cmh * wv.z; pa[3] += cmh * wv.w;
        }
        u16 xe[4]; *(uint2*)xe = xv;
        u16 ge[4]; *(uint2*)ge = gv;
        float e0 = dv.x + s * pv.x, e1 = dv.y + s * pv.y;
        float e2 = dv.z + s * pv.z, e3 = dv.w + s * pv.w;
        float4 o;
        o.x = e0 + b2f(xe[0]) * b2f(ge[0]) * sigm(pa[0]);
        o.y = e1 + b2f(xe[1]) * b2f(ge[1]) * sigm(pa[1]);
        o.z = e2 + b2f(xe[2]) * b2f(ge[2]) * sigm(pa[2]);
        o.w = e3 + b2f(xe[3]) * b2f(ge[3]) * sigm(pa[3]);
        *(float4*)&out[((size_t)b * 1290 + 290 + j) * 256 + c4] = o;
    }
}

extern "C" void kernel_launch(void* const* d_in, const int* in_sizes, int n_in,
                              void* d_out, int out_size, void* d_ws, size_t ws_size,
                              hipStream_t stream) {
    (void)in_sizes; (void)n_in; (void)out_size;
    const float* drug    = (const float*)d_in[0];
    const float* prot    = (const float*)d_in[1];
    const float* scale_d = (const float*)d_in[2];
    const float* scale_p = (const float*)d_in[3];

    char* ws = (char*)d_ws;
    size_t off = 0;
    auto alloc = [&](size_t bytes) -> void* {
        void* p = ws + off;
        off += (bytes + 255) & ~(size_t)255;
        return p;
    };
    float* pe   = (float*)alloc((size_t)1000 * 256 * 4);
    u16* e_d    = (u16*)alloc((size_t)MD * 256 * 2);
    u16* e_p    = (u16*)alloc((size_t)MP * 256 * 2);
    u16* wt     = (u16*)alloc((size_t)10 * 65536 * 2);
    u16* Qd     = (u16*)alloc((size_t)MD * 256 * 2);
    u16* Kd     = (u16*)alloc((size_t)MD * 256 * 2);
    u16* Vd     = (u16*)alloc((size_t)MD * 256 * 2);
    u16* gate_d = (u16*)alloc((size_t)MD * 256 * 2);
    u16* Kp     = (u16*)alloc((size_t)MP * 256 * 2);
    u16* Vp     = (u16*)alloc((size_t)MP * 256 * 2);
    u16* Qp     = (u16*)alloc((size_t)MP * 256 * 2);
    u16* gate_p = (u16*)alloc((size_t)MP * 256 * 2);
    u16* ctxd   = (u16*)alloc((size_t)MD * 256 * 2);
    u16* ctxp   = (u16*)alloc((size_t)MP * 256 * 2);
    float* cm   = (float*)alloc((size_t)MP * 8 * 4);
    u16* Xd     = (u16*)alloc((size_t)MD * 256 * 2);
    u16* Xp     = (u16*)alloc((size_t)MP * 256 * 2);
    if (off > ws_size) return;

    pe_kernel<<<1000, 256, 0, stream>>>(pe);

    WPtrs wp;
    const int wsrc[10] = {4, 12, 14, 25, 6, 8, 10, 27, 16, 18};
    for (int m = 0; m < 10; m++) wp.w[m] = (const float*)d_in[wsrc[m]];
    wprep_kernel<<<dim3(16, 10), 256, 0, stream>>>(wp, wt);

    eadd_kernel<<<(MD + MP) / 4, 256, 0, stream>>>(drug, prot, scale_d, scale_p, pe, e_d, e_p);

    auto W = [&](int slot) { return wt + (size_t)slot * 65536; };
    GCfg8 pc;
    pc.c[0] = { e_d, W(0), (const float*)d_in[5],  Qd,     145, 0 };
    pc.c[1] = { e_d, W(1), (const float*)d_in[13], Kd,     145, 0 };
    pc.c[2] = { e_d, W(2), (const float*)d_in[15], Vd,     145, 0 };
    pc.c[3] = { e_d, W(3), (const float*)d_in[26], gate_d, 145, 1 };
    pc.c[4] = { e_p, W(4), (const float*)d_in[7],  Kp,     500, 0 };
    pc.c[5] = { e_p, W(5), (const float*)d_in[9],  Vp,     500, 0 };
    pc.c[6] = { e_p, W(6), (const float*)d_in[11], Qp,     500, 0 };
    pc.c[7] = { e_p, W(7), (const float*)d_in[28], gate_p, 500, 1 };
    gemm_kernel<<<dim3(500, 4, 8), 256, 0, stream>>>(pc);

    attn_kernel<<<256, 512, 0, stream>>>(Qd, Kd, Vd, Kp, Vp, Qp,
                                         (const float*)d_in[20], ctxd, ctxp, cm);

    GCfg8 oc = pc;
    oc.c[0] = { ctxd, W(8), (const float*)d_in[17], Xd, 145, 0 };
    oc.c[1] = { ctxp, W(9), (const float*)d_in[19], Xp, 500, 0 };
    gemm_kernel<<<dim3(500, 4, 2), 256, 0, stream>>>(oc);

    combine_kernel<<<(MD + MP) / 4, 256, 0, stream>>>(drug, prot, scale_d, scale_p, pe,
        Xd, Xp, gate_d, gate_p, cm,
        (const float*)d_in[21], (const float*)d_in[22],
        (const float*)d_in[23], (const float*)d_in[24],
        (float*)d_out);
}

// Round 4
// 348.499 us; speedup vs baseline: 1.0001x; 1.0001x over previous
//
#include <hip/hip_runtime.h>
#include <math.h>

typedef __attribute__((ext_vector_type(8))) short bf16x8;
typedef __attribute__((ext_vector_type(4))) float f32x4;
typedef unsigned short u16;
typedef unsigned int u32;

#define DEVFN static __device__ __forceinline__

constexpr int NB  = 32;
constexpr int DLn = 290;
constexpr int PLc = 1000;
constexpr int MD  = NB * DLn;   // 9280
constexpr int MP  = NB * PLc;   // 32000

DEVFN u16 f2b(float f) {
    u32 u = __builtin_bit_cast(u32, f);
    u32 r = u + 0x7fffu + ((u >> 16) & 1u);
    return (u16)(r >> 16);
}
DEVFN float b2f(u16 s) { return __builtin_bit_cast(float, (u32)s << 16); }
DEVFN float sigm(float x) { return 1.0f / (1.0f + __expf(-x)); }

// ---------------- PE table ----------------
__global__ void pe_kernel(float* __restrict__ pe) {
    int p = blockIdx.x, c = threadIdx.x;
    float div = __expf((float)(c & ~1) * (-9.210340371976184f / 256.0f));
    float ang = (float)p * div;
    pe[p * 256 + c] = (c & 1) ? cosf(ang) : sinf(ang);
}

// ---------------- e = x + scale*pe (bf16), 4 cols/thread ----------------
__global__ __launch_bounds__(256) void eadd_kernel(
        const float* __restrict__ drug, const float* __restrict__ prot,
        const float* __restrict__ scale_d, const float* __restrict__ scale_p,
        const float* __restrict__ pe,
        u16* __restrict__ e_d, u16* __restrict__ e_p) {
    int idx = blockIdx.x * 256 + threadIdx.x;
    int r = idx >> 6, c4 = (idx & 63) * 4;
    if (r < MD) {
        int i = r % DLn;
        float s = scale_d[0];
        float4 dv = *(const float4*)&drug[(size_t)r * 256 + c4];
        float4 pv = *(const float4*)&pe[i * 256 + c4];
        u16 o[4];
        o[0] = f2b(dv.x + s * pv.x); o[1] = f2b(dv.y + s * pv.y);
        o[2] = f2b(dv.z + s * pv.z); o[3] = f2b(dv.w + s * pv.w);
        *(uint2*)&e_d[(size_t)r * 256 + c4] = *(uint2*)o;
    } else {
        int rr = r - MD;
        int j = rr % PLc;
        float s = scale_p[0];
        float4 dv = *(const float4*)&prot[(size_t)rr * 256 + c4];
        float4 pv = *(const float4*)&pe[j * 256 + c4];
        u16 o[4];
        o[0] = f2b(dv.x + s * pv.x); o[1] = f2b(dv.y + s * pv.y);
        o[2] = f2b(dv.z + s * pv.z); o[3] = f2b(dv.w + s * pv.w);
        *(uint2*)&e_p[(size_t)rr * 256 + c4] = *(uint2*)o;
    }
}

// ---------------- weight prep: WT[n][k] bf16, LDS transpose ----------------
struct WPtrs { const float* w[10]; };
__global__ __launch_bounds__(256) void wprep_kernel(WPtrs wp, u16* __restrict__ wt) {
    __shared__ u16 t[64][66];
    int m = blockIdx.y, tile = blockIdx.x;
    int k0 = (tile >> 2) * 64, n0 = (tile & 3) * 64;
    const float* w = wp.w[m];
    int r = threadIdx.x >> 6, c = threadIdx.x & 63;
    #pragma unroll
    for (int q = 0; q < 16; q++) {
        int rr = r + q * 4;
        t[rr][c] = f2b(w[(size_t)(k0 + rr) * 256 + n0 + c]);
    }
    __syncthreads();
    #pragma unroll
    for (int q = 0; q < 16; q++) {
        int rr = r + q * 4;
        wt[((size_t)m << 16) + (size_t)(n0 + rr) * 256 + k0 + c] = t[c][rr];
    }
}

// ---------------- GEMM: C[M,256] = A[M,256] @ WT^T + bias, BK=256 one phase ----------------
struct GCfg { const u16* A; const u16* BT; const float* bias; u16* C; int mtiles; int sig; };
struct GCfg8 { GCfg c[8]; };

__global__ __launch_bounds__(256) void gemm_kernel(GCfg8 cfgs) {
    const GCfg cfg = cfgs.c[blockIdx.z];
    const int mt = blockIdx.x;
    if (mt >= cfg.mtiles) return;
    const int nt = blockIdx.y;
    __shared__ u16 As[64][266];
    __shared__ u16 Bs[64][266];
    const int tid = threadIdx.x;
    const int lane = tid & 63, w = tid >> 6, ln = lane & 15, g = lane >> 4;
    const int lr = tid >> 2, lc = tid & 3;
    const u16* Ag = cfg.A + (size_t)(mt * 64 + lr) * 256 + lc * 8;
    const u16* Bg = cfg.BT + (size_t)(nt * 64 + lr) * 256 + lc * 8;
    uint4 av[8], bv[8];
    #pragma unroll
    for (int kk = 0; kk < 8; kk++) {
        av[kk] = *(const uint4*)(Ag + kk * 32);
        bv[kk] = *(const uint4*)(Bg + kk * 32);
    }
    #pragma unroll
    for (int kk = 0; kk < 8; kk++) {
        *(uint4*)&As[lr][lc * 8 + kk * 32] = av[kk];
        *(uint4*)&Bs[lr][lc * 8 + kk * 32] = bv[kk];
    }
    __syncthreads();
    const int m0 = (w >> 1) * 32, n0 = (w & 1) * 32;
    f32x4 acc[2][2] = {};
    #pragma unroll
    for (int k0 = 0; k0 < 8; k0++) {
        #pragma unroll
        for (int mi = 0; mi < 2; mi++) {
            bf16x8 af = *(const bf16x8*)&As[m0 + mi * 16 + ln][k0 * 32 + g * 8];
            #pragma unroll
            for (int ni = 0; ni < 2; ni++) {
                bf16x8 bfv = *(const bf16x8*)&Bs[n0 + ni * 16 + ln][k0 * 32 + g * 8];
                acc[mi][ni] = __builtin_amdgcn_mfma_f32_16x16x32_bf16(af, bfv, acc[mi][ni], 0, 0, 0);
            }
        }
    }
    #pragma unroll
    for (int mi = 0; mi < 2; mi++) {
        #pragma unroll
        for (int ni = 0; ni < 2; ni++) {
            const int n = nt * 64 + n0 + ni * 16 + ln;
            const float bb = cfg.bias[n];
            const int rowb = mt * 64 + m0 + mi * 16 + g * 4;
            #pragma unroll
            for (int r = 0; r < 4; r++) {
                float v = acc[mi][ni][r] + bb;
                if (cfg.sig) v = sigm(v);
                cfg.C[(size_t)(rowb + r) * 256 + n] = f2b(v);
            }
        }
    }
}

// ---------------- attention: one block per (b,h), no-max softmax, 2 sweeps ----------------
// LDS strides dword-odd (74 u16 = 37 dw, 330 u16 = 165 dw) to reduce bank conflicts.
// Pad j>=PLc unmasked: zero-staged K' gives S=0, exp=1; row sums corrected by -24;
// padded P multiplies zero-staged Vp/Vd so context is exact.
__global__ __launch_bounds__(512) void attn_kernel(
        const u16* __restrict__ Qd, const u16* __restrict__ Kd, const u16* __restrict__ Vd,
        const u16* __restrict__ Kp, const u16* __restrict__ Vp, const u16* __restrict__ Qp,
        const float* __restrict__ alpha,
        u16* __restrict__ ctx_d, u16* __restrict__ ctx_p, float* __restrict__ cm) {
    __shared__ u16 Ks[2][64][74];                     // K' = [Kp;Qp] tiles, dbuf
    __shared__ union {
        struct { u16 VpT[2][32][74]; u16 Pm[320][74]; } s1;   // sweep1
        struct { u16 PT[64][330]; u16 VdT[32][330]; } s2;     // sweep2
    } U;
    __shared__ float r_l[320];
    __shared__ float colpart[8][64];

    const int bh = blockIdx.x, b = bh >> 3, h = bh & 7;
    const int tid = threadIdx.x;
    const int w = tid >> 6, lane = tid & 63, ln = lane & 15, g = lane >> 4;

    const float a = sigm(alpha[0]);
    const float inv = 0.1767766952966369f;
    const float sa = a * inv, sb = (1.0f - a) * inv;
    const int nmt = (w < 4) ? 3 : 2;
    const int mtsA[3] = { w, w + 8, w + 16 };

    const size_t rbd = (size_t)b * DLn * 256 + h * 32;
    const size_t rbp = (size_t)b * PLc * 256 + h * 32;

    // ---- Q' fragments in registers (scaled, masked) ----
    bf16x8 Qf[3][2];
    #pragma unroll
    for (int t = 0; t < 3; t++) {
        const int i = mtsA[t] * 16 + ln;
        #pragma unroll
        for (int ks = 0; ks < 2; ks++) {
            u16 o[8] = {0,0,0,0,0,0,0,0};
            if (t < nmt && i < DLn) {
                const u16* src = (ks ? Kd : Qd) + rbd + (size_t)i * 256 + g * 8;
                const float s = ks ? sb : sa;
                uint4 v = *(const uint4*)src;
                u16 e[8]; *(uint4*)e = v;
                #pragma unroll
                for (int q = 0; q < 8; q++) o[q] = f2b(b2f(e[q]) * s);
            }
            Qf[t][ks] = *(bf16x8*)o;
        }
    }

    // staging thread mappings
    const int s_jj = tid >> 3, s_ch = tid & 7;
    const u16* s_src = ((s_ch >> 2) ? Qp : Kp) + rbp + (s_ch & 3) * 8;
    const int v_j = tid & 63, v_d0 = (tid >> 6) * 4;

    // ---- prologue: stage tile 0 ----
    {
        int j = s_jj;
        uint4 kv = (j < PLc) ? *(const uint4*)(s_src + (size_t)j * 256) : make_uint4(0,0,0,0);
        uint2 vv = (v_j < PLc) ? *(const uint2*)(Vp + rbp + (size_t)v_j * 256 + v_d0) : make_uint2(0,0);
        *(uint4*)&Ks[0][s_jj][s_ch * 8] = kv;
        u16 e[4]; *(uint2*)e = vv;
        #pragma unroll
        for (int q = 0; q < 4; q++) U.s1.VpT[0][v_d0 + q][v_j] = e[q];
    }
    __syncthreads();

    // ---- sweep 1: S^T orientation -> rowsums + ctx_d~ ----
    float rs[3] = {0.f, 0.f, 0.f};
    f32x4 accd[3][2] = {};
    for (int jt = 0; jt < 16; jt++) {
        const int cur = jt & 1, j0 = jt * 64;
        const int jn = j0 + 64 + s_jj;
        uint4 kv = (jn < PLc) ? *(const uint4*)(s_src + (size_t)jn * 256) : make_uint4(0,0,0,0);
        const int vn = j0 + 64 + v_j;
        uint2 vv = (vn < PLc) ? *(const uint2*)(Vp + rbp + (size_t)vn * 256 + v_d0) : make_uint2(0,0);

        bf16x8 kf[4][2];
        #pragma unroll
        for (int js = 0; js < 4; js++)
            #pragma unroll
            for (int ks = 0; ks < 2; ks++)
                kf[js][ks] = *(const bf16x8*)&Ks[cur][js * 16 + ln][ks * 32 + g * 8];

        #pragma unroll
        for (int t = 0; t < 3; t++) {
            if (t >= nmt) break;
            const int mt = mtsA[t];
            f32x4 acc[4] = {};
            #pragma unroll
            for (int ks = 0; ks < 2; ks++)
                #pragma unroll
                for (int js = 0; js < 4; js++)
                    acc[js] = __builtin_amdgcn_mfma_f32_16x16x32_bf16(kf[js][ks], Qf[t][ks], acc[js], 0, 0, 0);
            const int irow = mt * 16 + ln;
            #pragma unroll
            for (int js = 0; js < 4; js++) {
                u16 pb[4];
                float psum = 0.f;
                #pragma unroll
                for (int r = 0; r < 4; r++) {
                    float p = __expf(acc[js][r]);
                    psum += p;
                    pb[r] = f2b(p);
                }
                rs[t] += psum;
                *(ushort4*)&U.s1.Pm[irow][js * 16 + g * 4] = *(ushort4*)pb;
            }
        }
        // ctx_d accumulate (wave-local Pm rows)
        #pragma unroll
        for (int t = 0; t < 3; t++) {
            if (t >= nmt) break;
            const int mt = mtsA[t];
            #pragma unroll
            for (int ks2 = 0; ks2 < 2; ks2++) {
                bf16x8 af = *(const bf16x8*)&U.s1.Pm[mt * 16 + ln][ks2 * 32 + g * 8];
                #pragma unroll
                for (int nd = 0; nd < 2; nd++) {
                    bf16x8 bv = *(const bf16x8*)&U.s1.VpT[cur][nd * 16 + ln][ks2 * 32 + g * 8];
                    accd[t][nd] = __builtin_amdgcn_mfma_f32_16x16x32_bf16(af, bv, accd[t][nd], 0, 0, 0);
                }
            }
        }
        *(uint4*)&Ks[cur ^ 1][s_jj][s_ch * 8] = kv;
        {
            u16 e[4]; *(uint2*)e = vv;
            #pragma unroll
            for (int q = 0; q < 4; q++) U.s1.VpT[cur ^ 1][v_d0 + q][v_j] = e[q];
        }
        __syncthreads();
    }

    // ---- row sums -> reciprocals (subtract the 24 pad-j contributions) ----
    #pragma unroll
    for (int t = 0; t < 3; t++) {
        float v = rs[t];
        v += __shfl_xor(v, 16);
        v += __shfl_xor(v, 32);
        rs[t] = v;
    }
    if (g == 0) {
        #pragma unroll
        for (int t = 0; t < 3; t++) {
            if (t >= nmt) break;
            const int i = mtsA[t] * 16 + ln;
            r_l[i] = (i < DLn) ? 1.0f / (rs[t] - 24.0f) : 0.0f;
        }
    }
    __syncthreads();

    // ---- ctx_d write (scaled), VdTn build, stage Ks tile0 ----
    #pragma unroll
    for (int t = 0; t < 3; t++) {
        if (t >= nmt) break;
        const int mt = mtsA[t];
        #pragma unroll
        for (int r = 0; r < 4; r++) {
            const int i = mt * 16 + g * 4 + r;
            if (i < DLn) {
                const float ri = r_l[i];
                #pragma unroll
                for (int nd = 0; nd < 2; nd++)
                    ctx_d[rbd + (size_t)i * 256 + nd * 16 + ln] = f2b(accd[t][nd][r] * ri);
            }
        }
    }
    for (int c = tid; c < 320 * 8; c += 512) {
        const int i = c >> 3, d0 = (c & 7) * 4;
        u16 o[4] = {0,0,0,0};
        if (i < DLn) {
            const float ri = r_l[i];
            uint2 v = *(const uint2*)(Vd + rbd + (size_t)i * 256 + d0);
            u16 e[4]; *(uint2*)e = v;
            #pragma unroll
            for (int q = 0; q < 4; q++) o[q] = f2b(b2f(e[q]) * ri);
        }
        #pragma unroll
        for (int q = 0; q < 4; q++) U.s2.VdT[d0 + q][i] = o[q];
    }
    {
        int j = s_jj;
        uint4 kv = (j < PLc) ? *(const uint4*)(s_src + (size_t)j * 256) : make_uint4(0,0,0,0);
        *(uint4*)&Ks[0][s_jj][s_ch * 8] = kv;
    }
    float rr[3][4];
    #pragma unroll
    for (int t = 0; t < 3; t++)
        #pragma unroll
        for (int r = 0; r < 4; r++)
            rr[t][r] = (t < nmt) ? r_l[mtsA[t] * 16 + g * 4 + r] : 0.0f;
    __syncthreads();

    // ---- sweep 2: S orientation -> ctx_p + column means ----
    for (int jt = 0; jt < 16; jt++) {
        const int cur = jt & 1, j0 = jt * 64;
        const int jn = j0 + 64 + s_jj;
        uint4 kv = (jn < PLc) ? *(const uint4*)(s_src + (size_t)jn * 256) : make_uint4(0,0,0,0);

        bf16x8 kf[4][2];
        #pragma unroll
        for (int js = 0; js < 4; js++)
            #pragma unroll
            for (int ks = 0; ks < 2; ks++)
                kf[js][ks] = *(const bf16x8*)&Ks[cur][js * 16 + ln][ks * 32 + g * 8];

        float csl[4] = {0.f, 0.f, 0.f, 0.f};
        #pragma unroll
        for (int t = 0; t < 3; t++) {
            if (t >= nmt) break;
            const int mt = mtsA[t];
            f32x4 acc[4] = {};
            #pragma unroll
            for (int ks = 0; ks < 2; ks++)
                #pragma unroll
                for (int js = 0; js < 4; js++)
                    acc[js] = __builtin_amdgcn_mfma_f32_16x16x32_bf16(Qf[t][ks], kf[js][ks], acc[js], 0, 0, 0);
            #pragma unroll
            for (int js = 0; js < 4; js++) {
                u16 pb[4];
                #pragma unroll
                for (int r = 0; r < 4; r++) {
                    float p = __expf(acc[js][r]);
                    csl[js] += p * rr[t][r];
                    pb[r] = f2b(p);
                }
                *(ushort4*)&U.s2.PT[js * 16 + ln][mt * 16 + g * 4] = *(ushort4*)pb;
            }
        }
        #pragma unroll
        for (int js = 0; js < 4; js++) {
            float v = csl[js];
            v += __shfl_xor(v, 16);
            v += __shfl_xor(v, 32);
            csl[js] = v;
        }
        if (g == 0) {
            #pragma unroll
            for (int js = 0; js < 4; js++) colpart[w][js * 16 + ln] = csl[js];
        }
        *(uint4*)&Ks[cur ^ 1][s_jj][s_ch * 8] = kv;
        __syncthreads();

        // phase 2: ctx_p tile (all 8 waves) + cm (wave 0)
        {
            const int js2 = w & 3, ds2 = w >> 2;
            f32x4 ap = {};
            #pragma unroll
            for (int k = 0; k < 10; k++) {
                bf16x8 af = *(const bf16x8*)&U.s2.PT[js2 * 16 + ln][k * 32 + g * 8];
                bf16x8 bv = *(const bf16x8*)&U.s2.VdT[ds2 * 16 + ln][k * 32 + g * 8];
                ap = __builtin_amdgcn_mfma_f32_16x16x32_bf16(af, bv, ap, 0, 0, 0);
            }
            const int d = ds2 * 16 + ln;
            #pragma unroll
            for (int r = 0; r < 4; r++) {
                const int j = j0 + js2 * 16 + g * 4 + r;
                if (j < PLc) ctx_p[rbp + (size_t)j * 256 + d] = f2b(ap[r]);
            }
        }
        if (w == 0) {
            float tot = 0.f;
            #pragma unroll
            for (int ww = 0; ww < 8; ww++) tot += colpart[ww][lane];
            const int j = j0 + lane;
            if (j < PLc) cm[(size_t)(b * PLc + j) * 8 + h] = tot * (1.0f / 290.0f);
        }
        __syncthreads();
    }
}

// ---------------- final combine, 4 cols/thread ----------------
__global__ __launch_bounds__(256) void combine_kernel(
        const float* __restrict__ drug, const float* __restrict__ prot,
        const float* __restrict__ scale_d, const float* __restrict__ scale_p,
        const float* __restrict__ pe,
        const u16* __restrict__ Xd, const u16* __restrict__ Xp,
        const u16* __restrict__ gate_d, const u16* __restrict__ gate_p,
        const float* __restrict__ cm,
        const float* __restrict__ w_fc_dp, const float* __restrict__ b_fc_dp,
        const float* __restrict__ w_fc_pd, const float* __restrict__ b_fc_pd,
        float* __restrict__ out) {
    int idx = blockIdx.x * 256 + threadIdx.x;
    int r = idx >> 6, c4 = (idx & 63) * 4;
    if (r < MD) {
        int b = r / DLn, i = r % DLn;
        float s = scale_d[0];
        float4 dv = *(const float4*)&drug[(size_t)r * 256 + c4];
        float4 pv = *(const float4*)&pe[i * 256 + c4];
        uint2 xv = *(const uint2*)&Xd[(size_t)r * 256 + c4];
        uint2 gv = *(const uint2*)&gate_d[(size_t)r * 256 + c4];
        float4 bb = *(const float4*)&b_fc_dp[c4];
        float da[4] = { bb.x, bb.y, bb.z, bb.w };
        #pragma unroll
        for (int hh = 0; hh < 8; hh++) {
            float4 wv = *(const float4*)&w_fc_dp[hh * 256 + c4];
            da[0] += 0.001f * wv.x; da[1] += 0.001f * wv.y;
            da[2] += 0.001f * wv.z; da[3] += 0.001f * wv.w;
        }
        u16 xe[4]; *(uint2*)xe = xv;
        u16 ge[4]; *(uint2*)ge = gv;
        float e0 = dv.x + s * pv.x, e1 = dv.y + s * pv.y;
        float e2 = dv.z + s * pv.z, e3 = dv.w + s * pv.w;
        float4 o;
        o.x = e0 + b2f(xe[0]) * b2f(ge[0]) * sigm(da[0]);
        o.y = e1 + b2f(xe[1]) * b2f(ge[1]) * sigm(da[1]);
        o.z = e2 + b2f(xe[2]) * b2f(ge[2]) * sigm(da[2]);
        o.w = e3 + b2f(xe[3]) * b2f(ge[3]) * sigm(da[3]);
        *(float4*)&out[((size_t)b * 1290 + i) * 256 + c4] = o;
    } else {
        int rr = r - MD;
        int b = rr / PLc, j = rr % PLc;
        float s = scale_p[0];
        float4 dv = *(const float4*)&prot[(size_t)rr * 256 + c4];
        float4 pv = *(const float4*)&pe[j * 256 + c4];
        uint2 xv = *(const uint2*)&Xp[(size_t)rr * 256 + c4];
        uint2 gv = *(const uint2*)&gate_p[(size_t)rr * 256 + c4];
        float4 bb = *(const float4*)&b_fc_pd[c4];
        float pa[4] = { bb.x, bb.y, bb.z, bb.w };
        #pragma unroll
        for (int hh = 0; hh < 8; hh++) {
            float cmh = cm[(size_t)rr * 8 + hh];
            float4 wv = *(const float4*)&w_fc_pd[hh * 256 + c4];
            pa[0] += cmh * wv.x; pa[1] += cmh * wv.y;
            pa[2] += cmh * wv.z; pa[3] += cmh * wv.w;
        }
        u16 xe[4]; *(uint2*)xe = xv;
        u16 ge[4]; *(uint2*)ge = gv;
        float e0 = dv.x + s * pv.x, e1 = dv.y + s * pv.y;
        float e2 = dv.z + s * pv.z, e3 = dv.w + s * pv.w;
        float4 o;
        o.x = e0 + b2f(xe[0]) * b2f(ge[0]) * sigm(pa[0]);
        o.y = e1 + b2f(xe[1]) * b2f(ge[1]) * sigm(pa[1]);
        o.z = e2 + b2f(xe[2]) * b2f(ge[2]) * sigm(pa[2]);
        o.w = e3 + b2f(xe[3]) * b2f(ge[3]) * sigm(pa[3]);
        *(float4*)&out[((size_t)b * 1290 + 290 + j) * 256 + c4] = o;
    }
}

extern "C" void kernel_launch(void* const* d_in, const int* in_sizes, int n_in,
                              void* d_out, int out_size, void* d_ws, size_t ws_size,
                              hipStream_t stream) {
    (void)in_sizes; (void)n_in; (void)out_size;
    const float* drug    = (const float*)d_in[0];
    const float* prot    = (const float*)d_in[1];
    const float* scale_d = (const float*)d_in[2];
    const float* scale_p = (const float*)d_in[3];

    char* ws = (char*)d_ws;
    size_t off = 0;
    auto alloc = [&](size_t bytes) -> void* {
        void* p = ws + off;
        off += (bytes + 255) & ~(size_t)255;
        return p;
    };
    float* pe   = (float*)alloc((size_t)1000 * 256 * 4);
    u16* e_d    = (u16*)alloc((size_t)MD * 256 * 2);
    u16* e_p    = (u16*)alloc((size_t)MP * 256 * 2);
    u16* wt     = (u16*)alloc((size_t)10 * 65536 * 2);
    u16* Qd     = (u16*)alloc((size_t)MD * 256 * 2);
    u16* Kd     = (u16*)alloc((size_t)MD * 256 * 2);
    u16* Vd     = (u16*)alloc((size_t)MD * 256 * 2);
    u16* gate_d = (u16*)alloc((size_t)MD * 256 * 2);
    u16* Kp     = (u16*)alloc((size_t)MP * 256 * 2);
    u16* Vp     = (u16*)alloc((size_t)MP * 256 * 2);
    u16* Qp     = (u16*)alloc((size_t)MP * 256 * 2);
    u16* gate_p = (u16*)alloc((size_t)MP * 256 * 2);
    u16* ctxd   = (u16*)alloc((size_t)MD * 256 * 2);
    u16* ctxp   = (u16*)alloc((size_t)MP * 256 * 2);
    float* cm   = (float*)alloc((size_t)MP * 8 * 4);
    u16* Xd     = (u16*)alloc((size_t)MD * 256 * 2);
    u16* Xp     = (u16*)alloc((size_t)MP * 256 * 2);
    if (off > ws_size) return;

    pe_kernel<<<1000, 256, 0, stream>>>(pe);

    WPtrs wp;
    const int wsrc[10] = {4, 12, 14, 25, 6, 8, 10, 27, 16, 18};
    for (int m = 0; m < 10; m++) wp.w[m] = (const float*)d_in[wsrc[m]];
    wprep_kernel<<<dim3(16, 10), 256, 0, stream>>>(wp, wt);

    eadd_kernel<<<(MD + MP) / 4, 256, 0, stream>>>(drug, prot, scale_d, scale_p, pe, e_d, e_p);

    auto W = [&](int slot) { return wt + (size_t)slot * 65536; };
    GCfg8 pc;
    pc.c[0] = { e_d, W(0), (const float*)d_in[5],  Qd,     145, 0 };
    pc.c[1] = { e_d, W(1), (const float*)d_in[13], Kd,     145, 0 };
    pc.c[2] = { e_d, W(2), (const float*)d_in[15], Vd,     145, 0 };
    pc.c[3] = { e_d, W(3), (const float*)d_in[26], gate_d, 145, 1 };
    pc.c[4] = { e_p, W(4), (const float*)d_in[7],  Kp,     500, 0 };
    pc.c[5] = { e_p, W(5), (const float*)d_in[9],  Vp,     500, 0 };
    pc.c[6] = { e_p, W(6), (const float*)d_in[11], Qp,     500, 0 };
    pc.c[7] = { e_p, W(7), (const float*)d_in[28], gate_p, 500, 1 };
    gemm_kernel<<<dim3(500, 4, 8), 256, 0, stream>>>(pc);

    attn_kernel<<<256, 512, 0, stream>>>(Qd, Kd, Vd, Kp, Vp, Qp,
                                         (const float*)d_in[20], ctxd, ctxp, cm);

    GCfg8 oc = pc;
    oc.c[0] = { ctxd, W(8), (const float*)d_in[17], Xd, 145, 0 };
    oc.c[1] = { ctxp, W(9), (const float*)d_in[19], Xp, 500, 0 };
    gemm_kernel<<<dim3(500, 4, 2), 256, 0, stream>>>(oc);

    combine_kernel<<<(MD + MP) / 4, 256, 0, stream>>>(drug, prot, scale_d, scale_p, pe,
        Xd, Xp, gate_d, gate_p, cm,
        (const float*)d_in[21], (const float*)d_in[22],
        (const float*)d_in[23], (const float*)d_in[24],
        (float*)d_out);
}

// Round 5
// 205.270 us; speedup vs baseline: 1.6980x; 1.6978x over previous
//
#include <hip/hip_runtime.h>
#include <math.h>

typedef __attribute__((ext_vector_type(8))) short bf16x8;
typedef __attribute__((ext_vector_type(4))) float f32x4;
typedef unsigned short u16;
typedef unsigned int u32;

#define DEVFN static __device__ __forceinline__

constexpr int NB  = 32;
constexpr int DLn = 290;
constexpr int PLc = 1000;
constexpr int MD  = NB * DLn;   // 9280
constexpr int MP  = NB * PLc;   // 32000

DEVFN u16 f2b(float f) {
    u32 u = __builtin_bit_cast(u32, f);
    u32 r = u + 0x7fffu + ((u >> 16) & 1u);
    return (u16)(r >> 16);
}
DEVFN float b2f(u16 s) { return __builtin_bit_cast(float, (u32)s << 16); }
DEVFN float sigm(float x) { return 1.0f / (1.0f + __expf(-x)); }
// XOR-swizzled LDS index (u16 units). stride must be multiple of 8 u16 (16B).
// Keeps 16B alignment (flips only bits 3-5 of the column) and makes the 16B
// granule = (col/8) ^ (row&7) -> conflict-free for strided fragment reads.
DEVFN int sw(int row, int col, int stride) { return row * stride + (col ^ ((row & 7) << 3)); }

// ---------------- PE table ----------------
__global__ void pe_kernel(float* __restrict__ pe) {
    int p = blockIdx.x, c = threadIdx.x;
    float div = __expf((float)(c & ~1) * (-9.210340371976184f / 256.0f));
    float ang = (float)p * div;
    pe[p * 256 + c] = (c & 1) ? cosf(ang) : sinf(ang);
}

// ---------------- e = x + scale*pe (bf16), 4 cols/thread ----------------
__global__ __launch_bounds__(256) void eadd_kernel(
        const float* __restrict__ drug, const float* __restrict__ prot,
        const float* __restrict__ scale_d, const float* __restrict__ scale_p,
        const float* __restrict__ pe,
        u16* __restrict__ e_d, u16* __restrict__ e_p) {
    int idx = blockIdx.x * 256 + threadIdx.x;
    int r = idx >> 6, c4 = (idx & 63) * 4;
    if (r < MD) {
        int i = r % DLn;
        float s = scale_d[0];
        float4 dv = *(const float4*)&drug[(size_t)r * 256 + c4];
        float4 pv = *(const float4*)&pe[i * 256 + c4];
        u16 o[4];
        o[0] = f2b(dv.x + s * pv.x); o[1] = f2b(dv.y + s * pv.y);
        o[2] = f2b(dv.z + s * pv.z); o[3] = f2b(dv.w + s * pv.w);
        *(uint2*)&e_d[(size_t)r * 256 + c4] = *(uint2*)o;
    } else {
        int rr = r - MD;
        int j = rr % PLc;
        float s = scale_p[0];
        float4 dv = *(const float4*)&prot[(size_t)rr * 256 + c4];
        float4 pv = *(const float4*)&pe[j * 256 + c4];
        u16 o[4];
        o[0] = f2b(dv.x + s * pv.x); o[1] = f2b(dv.y + s * pv.y);
        o[2] = f2b(dv.z + s * pv.z); o[3] = f2b(dv.w + s * pv.w);
        *(uint2*)&e_p[(size_t)rr * 256 + c4] = *(uint2*)o;
    }
}

// ---------------- weight prep: WT[n][k] bf16, LDS transpose ----------------
struct WPtrs { const float* w[10]; };
__global__ __launch_bounds__(256) void wprep_kernel(WPtrs wp, u16* __restrict__ wt) {
    __shared__ u16 t[64][66];
    int m = blockIdx.y, tile = blockIdx.x;
    int k0 = (tile >> 2) * 64, n0 = (tile & 3) * 64;
    const float* w = wp.w[m];
    int r = threadIdx.x >> 6, c = threadIdx.x & 63;
    #pragma unroll
    for (int q = 0; q < 16; q++) {
        int rr = r + q * 4;
        t[rr][c] = f2b(w[(size_t)(k0 + rr) * 256 + n0 + c]);
    }
    __syncthreads();
    #pragma unroll
    for (int q = 0; q < 16; q++) {
        int rr = r + q * 4;
        wt[((size_t)m << 16) + (size_t)(n0 + rr) * 256 + k0 + c] = t[c][rr];
    }
}

// ---------------- GEMM: C[M,256] = A[M,256] @ WT^T + bias, BK=256, swizzled LDS ----------------
struct GCfg { const u16* A; const u16* BT; const float* bias; u16* C; int mtiles; int sig; };
struct GCfg8 { GCfg c[8]; };

__global__ __launch_bounds__(256) void gemm_kernel(GCfg8 cfgs) {
    const GCfg cfg = cfgs.c[blockIdx.z];
    const int mt = blockIdx.x;
    if (mt >= cfg.mtiles) return;
    const int nt = blockIdx.y;
    __shared__ u16 As[64 * 256];
    __shared__ u16 Bs[64 * 256];
    const int tid = threadIdx.x;
    const int lane = tid & 63, w = tid >> 6, ln = lane & 15, g = lane >> 4;
    const int lr = tid >> 2, lc = tid & 3;
    const u16* Ag = cfg.A + (size_t)(mt * 64 + lr) * 256 + lc * 8;
    const u16* Bg = cfg.BT + (size_t)(nt * 64 + lr) * 256 + lc * 8;
    uint4 av[8], bv[8];
    #pragma unroll
    for (int kk = 0; kk < 8; kk++) {
        av[kk] = *(const uint4*)(Ag + kk * 32);
        bv[kk] = *(const uint4*)(Bg + kk * 32);
    }
    #pragma unroll
    for (int kk = 0; kk < 8; kk++) {
        *(uint4*)&As[sw(lr, lc * 8 + kk * 32, 256)] = av[kk];
        *(uint4*)&Bs[sw(lr, lc * 8 + kk * 32, 256)] = bv[kk];
    }
    __syncthreads();
    const int m0 = (w >> 1) * 32, n0 = (w & 1) * 32;
    f32x4 acc[2][2] = {};
    #pragma unroll
    for (int k0 = 0; k0 < 8; k0++) {
        #pragma unroll
        for (int mi = 0; mi < 2; mi++) {
            bf16x8 af = *(const bf16x8*)&As[sw(m0 + mi * 16 + ln, k0 * 32 + g * 8, 256)];
            #pragma unroll
            for (int ni = 0; ni < 2; ni++) {
                bf16x8 bfv = *(const bf16x8*)&Bs[sw(n0 + ni * 16 + ln, k0 * 32 + g * 8, 256)];
                acc[mi][ni] = __builtin_amdgcn_mfma_f32_16x16x32_bf16(af, bfv, acc[mi][ni], 0, 0, 0);
            }
        }
    }
    #pragma unroll
    for (int mi = 0; mi < 2; mi++) {
        #pragma unroll
        for (int ni = 0; ni < 2; ni++) {
            const int n = nt * 64 + n0 + ni * 16 + ln;
            const float bb = cfg.bias[n];
            const int rowb = mt * 64 + m0 + mi * 16 + g * 4;
            #pragma unroll
            for (int r = 0; r < 4; r++) {
                float v = acc[mi][ni][r] + bb;
                if (cfg.sig) v = sigm(v);
                cfg.C[(size_t)(rowb + r) * 256 + n] = f2b(v);
            }
        }
    }
}

// ---------------- attention: one block per (b,h), no-max softmax, 2 sweeps ----------------
// All LDS tiles: 16B-aligned rows + XOR swizzle (conflict-free ds_read_b128).
// Pad j>=PLc unmasked: zero-staged K' gives S=0, exp=1; row sums corrected by -24;
// padded P multiplies zero-staged Vp/Vd so context is exact.
__global__ __launch_bounds__(512) void attn_kernel(
        const u16* __restrict__ Qd, const u16* __restrict__ Kd, const u16* __restrict__ Vd,
        const u16* __restrict__ Kp, const u16* __restrict__ Vp, const u16* __restrict__ Qp,
        const float* __restrict__ alpha,
        u16* __restrict__ ctx_d, u16* __restrict__ ctx_p, float* __restrict__ cm) {
    __shared__ u16 Ks[2][64 * 64];                    // K' = [Kp;Qp] tiles, dbuf, stride 64
    __shared__ union {
        struct { u16 VpT[2][32 * 64]; u16 Pm[320 * 64]; } s1;   // sweep1
        struct { u16 PT[64 * 320]; u16 VdT[32 * 320]; } s2;     // sweep2
    } U;
    __shared__ float r_l[320];
    __shared__ float colpart[8][64];

    const int bh = blockIdx.x, b = bh >> 3, h = bh & 7;
    const int tid = threadIdx.x;
    const int w = tid >> 6, lane = tid & 63, ln = lane & 15, g = lane >> 4;

    const float a = sigm(alpha[0]);
    const float inv = 0.1767766952966369f;
    const float sa = a * inv, sb = (1.0f - a) * inv;
    const int nmt = (w < 4) ? 3 : 2;
    const int mtsA[3] = { w, w + 8, w + 16 };

    const size_t rbd = (size_t)b * DLn * 256 + h * 32;
    const size_t rbp = (size_t)b * PLc * 256 + h * 32;

    // ---- Q' fragments in registers (scaled, masked) ----
    bf16x8 Qf[3][2];
    #pragma unroll
    for (int t = 0; t < 3; t++) {
        const int i = mtsA[t] * 16 + ln;
        #pragma unroll
        for (int ks = 0; ks < 2; ks++) {
            u16 o[8] = {0,0,0,0,0,0,0,0};
            if (t < nmt && i < DLn) {
                const u16* src = (ks ? Kd : Qd) + rbd + (size_t)i * 256 + g * 8;
                const float s = ks ? sb : sa;
                uint4 v = *(const uint4*)src;
                u16 e[8]; *(uint4*)e = v;
                #pragma unroll
                for (int q = 0; q < 8; q++) o[q] = f2b(b2f(e[q]) * s);
            }
            Qf[t][ks] = *(bf16x8*)o;
        }
    }

    // staging thread mappings
    const int s_jj = tid >> 3, s_ch = tid & 7;
    const u16* s_src = ((s_ch >> 2) ? Qp : Kp) + rbp + (s_ch & 3) * 8;
    const int v_j = tid & 63, v_d0 = (tid >> 6) * 4;

    // ---- prologue: stage tile 0 ----
    {
        int j = s_jj;
        uint4 kv = (j < PLc) ? *(const uint4*)(s_src + (size_t)j * 256) : make_uint4(0,0,0,0);
        uint2 vv = (v_j < PLc) ? *(const uint2*)(Vp + rbp + (size_t)v_j * 256 + v_d0) : make_uint2(0,0);
        *(uint4*)&Ks[0][sw(s_jj, s_ch * 8, 64)] = kv;
        u16 e[4]; *(uint2*)e = vv;
        #pragma unroll
        for (int q = 0; q < 4; q++) U.s1.VpT[0][sw(v_d0 + q, v_j, 64)] = e[q];
    }
    __syncthreads();

    // ---- sweep 1: S^T orientation -> rowsums + ctx_d~ ----
    float rs[3] = {0.f, 0.f, 0.f};
    f32x4 accd[3][2] = {};
    for (int jt = 0; jt < 16; jt++) {
        const int cur = jt & 1, j0 = jt * 64;
        const int jn = j0 + 64 + s_jj;
        uint4 kv = (jn < PLc) ? *(const uint4*)(s_src + (size_t)jn * 256) : make_uint4(0,0,0,0);
        const int vn = j0 + 64 + v_j;
        uint2 vv = (vn < PLc) ? *(const uint2*)(Vp + rbp + (size_t)vn * 256 + v_d0) : make_uint2(0,0);

        bf16x8 kf[4][2];
        #pragma unroll
        for (int js = 0; js < 4; js++)
            #pragma unroll
            for (int ks = 0; ks < 2; ks++)
                kf[js][ks] = *(const bf16x8*)&Ks[cur][sw(js * 16 + ln, ks * 32 + g * 8, 64)];

        #pragma unroll
        for (int t = 0; t < 3; t++) {
            if (t >= nmt) break;
            const int mt = mtsA[t];
            f32x4 acc[4] = {};
            #pragma unroll
            for (int ks = 0; ks < 2; ks++)
                #pragma unroll
                for (int js = 0; js < 4; js++)
                    acc[js] = __builtin_amdgcn_mfma_f32_16x16x32_bf16(kf[js][ks], Qf[t][ks], acc[js], 0, 0, 0);
            const int irow = mt * 16 + ln;
            #pragma unroll
            for (int js = 0; js < 4; js++) {
                u16 pb[4];
                float psum = 0.f;
                #pragma unroll
                for (int r = 0; r < 4; r++) {
                    float p = __expf(acc[js][r]);
                    psum += p;
                    pb[r] = f2b(p);
                }
                rs[t] += psum;
                *(ushort4*)&U.s1.Pm[sw(irow, js * 16 + g * 4, 64)] = *(ushort4*)pb;
            }
        }
        // ctx_d accumulate (wave-local Pm rows)
        #pragma unroll
        for (int t = 0; t < 3; t++) {
            if (t >= nmt) break;
            const int mt = mtsA[t];
            #pragma unroll
            for (int ks2 = 0; ks2 < 2; ks2++) {
                bf16x8 af = *(const bf16x8*)&U.s1.Pm[sw(mt * 16 + ln, ks2 * 32 + g * 8, 64)];
                #pragma unroll
                for (int nd = 0; nd < 2; nd++) {
                    bf16x8 bv = *(const bf16x8*)&U.s1.VpT[cur][sw(nd * 16 + ln, ks2 * 32 + g * 8, 64)];
                    accd[t][nd] = __builtin_amdgcn_mfma_f32_16x16x32_bf16(af, bv, accd[t][nd], 0, 0, 0);
                }
            }
        }
        *(uint4*)&Ks[cur ^ 1][sw(s_jj, s_ch * 8, 64)] = kv;
        {
            u16 e[4]; *(uint2*)e = vv;
            #pragma unroll
            for (int q = 0; q < 4; q++) U.s1.VpT[cur ^ 1][sw(v_d0 + q, v_j, 64)] = e[q];
        }
        __syncthreads();
    }

    // ---- row sums -> reciprocals (subtract the 24 pad-j contributions) ----
    #pragma unroll
    for (int t = 0; t < 3; t++) {
        float v = rs[t];
        v += __shfl_xor(v, 16);
        v += __shfl_xor(v, 32);
        rs[t] = v;
    }
    if (g == 0) {
        #pragma unroll
        for (int t = 0; t < 3; t++) {
            if (t >= nmt) break;
            const int i = mtsA[t] * 16 + ln;
            r_l[i] = (i < DLn) ? 1.0f / (rs[t] - 24.0f) : 0.0f;
        }
    }
    __syncthreads();

    // ---- ctx_d write (scaled), VdTn build, stage Ks tile0 ----
    #pragma unroll
    for (int t = 0; t < 3; t++) {
        if (t >= nmt) break;
        const int mt = mtsA[t];
        #pragma unroll
        for (int r = 0; r < 4; r++) {
            const int i = mt * 16 + g * 4 + r;
            if (i < DLn) {
                const float ri = r_l[i];
                #pragma unroll
                for (int nd = 0; nd < 2; nd++)
                    ctx_d[rbd + (size_t)i * 256 + nd * 16 + ln] = f2b(accd[t][nd][r] * ri);
            }
        }
    }
    for (int c = tid; c < 320 * 8; c += 512) {
        const int i = c >> 3, d0 = (c & 7) * 4;
        u16 o[4] = {0,0,0,0};
        if (i < DLn) {
            const float ri = r_l[i];
            uint2 v = *(const uint2*)(Vd + rbd + (size_t)i * 256 + d0);
            u16 e[4]; *(uint2*)e = v;
            #pragma unroll
            for (int q = 0; q < 4; q++) o[q] = f2b(b2f(e[q]) * ri);
        }
        #pragma unroll
        for (int q = 0; q < 4; q++) U.s2.VdT[sw(d0 + q, i, 320)] = o[q];
    }
    {
        int j = s_jj;
        uint4 kv = (j < PLc) ? *(const uint4*)(s_src + (size_t)j * 256) : make_uint4(0,0,0,0);
        *(uint4*)&Ks[0][sw(s_jj, s_ch * 8, 64)] = kv;
    }
    float rr[3][4];
    #pragma unroll
    for (int t = 0; t < 3; t++)
        #pragma unroll
        for (int r = 0; r < 4; r++)
            rr[t][r] = (t < nmt) ? r_l[mtsA[t] * 16 + g * 4 + r] : 0.0f;
    __syncthreads();

    // ---- sweep 2: S orientation -> ctx_p + column means ----
    for (int jt = 0; jt < 16; jt++) {
        const int cur = jt & 1, j0 = jt * 64;
        const int jn = j0 + 64 + s_jj;
        uint4 kv = (jn < PLc) ? *(const uint4*)(s_src + (size_t)jn * 256) : make_uint4(0,0,0,0);

        bf16x8 kf[4][2];
        #pragma unroll
        for (int js = 0; js < 4; js++)
            #pragma unroll
            for (int ks = 0; ks < 2; ks++)
                kf[js][ks] = *(const bf16x8*)&Ks[cur][sw(js * 16 + ln, ks * 32 + g * 8, 64)];

        float csl[4] = {0.f, 0.f, 0.f, 0.f};
        #pragma unroll
        for (int t = 0; t < 3; t++) {
            if (t >= nmt) break;
            const int mt = mtsA[t];
            f32x4 acc[4] = {};
            #pragma unroll
            for (int ks = 0; ks < 2; ks++)
                #pragma unroll
                for (int js = 0; js < 4; js++)
                    acc[js] = __builtin_amdgcn_mfma_f32_16x16x32_bf16(Qf[t][ks], kf[js][ks], acc[js], 0, 0, 0);
            #pragma unroll
            for (int js = 0; js < 4; js++) {
                u16 pb[4];
                #pragma unroll
                for (int r = 0; r < 4; r++) {
                    float p = __expf(acc[js][r]);
                    csl[js] += p * rr[t][r];
                    pb[r] = f2b(p);
                }
                *(ushort4*)&U.s2.PT[sw(js * 16 + ln, mt * 16 + g * 4, 320)] = *(ushort4*)pb;
            }
        }
        #pragma unroll
        for (int js = 0; js < 4; js++) {
            float v = csl[js];
            v += __shfl_xor(v, 16);
            v += __shfl_xor(v, 32);
            csl[js] = v;
        }
        if (g == 0) {
            #pragma unroll
            for (int js = 0; js < 4; js++) colpart[w][js * 16 + ln] = csl[js];
        }
        *(uint4*)&Ks[cur ^ 1][sw(s_jj, s_ch * 8, 64)] = kv;
        __syncthreads();

        // phase 2: ctx_p tile (all 8 waves) + cm (wave 0)
        {
            const int js2 = w & 3, ds2 = w >> 2;
            f32x4 ap = {};
            #pragma unroll
            for (int k = 0; k < 10; k++) {
                bf16x8 af = *(const bf16x8*)&U.s2.PT[sw(js2 * 16 + ln, k * 32 + g * 8, 320)];
                bf16x8 bv = *(const bf16x8*)&U.s2.VdT[sw(ds2 * 16 + ln, k * 32 + g * 8, 320)];
                ap = __builtin_amdgcn_mfma_f32_16x16x32_bf16(af, bv, ap, 0, 0, 0);
            }
            const int d = ds2 * 16 + ln;
            #pragma unroll
            for (int r = 0; r < 4; r++) {
                const int j = j0 + js2 * 16 + g * 4 + r;
                if (j < PLc) ctx_p[rbp + (size_t)j * 256 + d] = f2b(ap[r]);
            }
        }
        if (w == 0) {
            float tot = 0.f;
            #pragma unroll
            for (int ww = 0; ww < 8; ww++) tot += colpart[ww][lane];
            const int j = j0 + lane;
            if (j < PLc) cm[(size_t)(b * PLc + j) * 8 + h] = tot * (1.0f / 290.0f);
        }
        __syncthreads();
    }
}

// ---------------- final combine, 4 cols/thread ----------------
__global__ __launch_bounds__(256) void combine_kernel(
        const float* __restrict__ drug, const float* __restrict__ prot,
        const float* __restrict__ scale_d, const float* __restrict__ scale_p,
        const float* __restrict__ pe,
        const u16* __restrict__ Xd, const u16* __restrict__ Xp,
        const u16* __restrict__ gate_d, const u16* __restrict__ gate_p,
        const float* __restrict__ cm,
        const float* __restrict__ w_fc_dp, const float* __restrict__ b_fc_dp,
        const float* __restrict__ w_fc_pd, const float* __restrict__ b_fc_pd,
        float* __restrict__ out) {
    int idx = blockIdx.x * 256 + threadIdx.x;
    int r = idx >> 6, c4 = (idx & 63) * 4;
    if (r < MD) {
        int b = r / DLn, i = r % DLn;
        float s = scale_d[0];
        float4 dv = *(const float4*)&drug[(size_t)r * 256 + c4];
        float4 pv = *(const float4*)&pe[i * 256 + c4];
        uint2 xv = *(const uint2*)&Xd[(size_t)r * 256 + c4];
        uint2 gv = *(const uint2*)&gate_d[(size_t)r * 256 + c4];
        float4 bb = *(const float4*)&b_fc_dp[c4];
        float da[4] = { bb.x, bb.y, bb.z, bb.w };
        #pragma unroll
        for (int hh = 0; hh < 8; hh++) {
            float4 wv = *(const float4*)&w_fc_dp[hh * 256 + c4];
            da[0] += 0.001f * wv.x; da[1] += 0.001f * wv.y;
            da[2] += 0.001f * wv.z; da[3] += 0.001f * wv.w;
        }
        u16 xe[4]; *(uint2*)xe = xv;
        u16 ge[4]; *(uint2*)ge = gv;
        float e0 = dv.x + s * pv.x, e1 = dv.y + s * pv.y;
        float e2 = dv.z + s * pv.z, e3 = dv.w + s * pv.w;
        float4 o;
        o.x = e0 + b2f(xe[0]) * b2f(ge[0]) * sigm(da[0]);
        o.y = e1 + b2f(xe[1]) * b2f(ge[1]) * sigm(da[1]);
        o.z = e2 + b2f(xe[2]) * b2f(ge[2]) * sigm(da[2]);
        o.w = e3 + b2f(xe[3]) * b2f(ge[3]) * sigm(da[3]);
        *(float4*)&out[((size_t)b * 1290 + i) * 256 + c4] = o;
    } else {
        int rr = r - MD;
        int b = rr / PLc, j = rr % PLc;
        float s = scale_p[0];
        float4 dv = *(const float4*)&prot[(size_t)rr * 256 + c4];
        float4 pv = *(const float4*)&pe[j * 256 + c4];
        uint2 xv = *(const uint2*)&Xp[(size_t)rr * 256 + c4];
        uint2 gv = *(const uint2*)&gate_p[(size_t)rr * 256 + c4];
        float4 bb = *(const float4*)&b_fc_pd[c4];
        float pa[4] = { bb.x, bb.y, bb.z, bb.w };
        #pragma unroll
        for (int hh = 0; hh < 8; hh++) {
            float cmh = cm[(size_t)rr * 8 + hh];
            float4 wv = *(const float4*)&w_fc_pd[hh * 256 + c4];
            pa[0] += cmh * wv.x; pa[1] += cmh * wv.y;
            pa[2] += cmh * wv.z; pa[3] += cmh * wv.w;
        }
        u16 xe[4]; *(uint2*)xe = xv;
        u16 ge[4]; *(uint2*)ge = gv;
        float e0 = dv.x + s * pv.x, e1 = dv.y + s * pv.y;
        float e2 = dv.z + s * pv.z, e3 = dv.w + s * pv.w;
        float4 o;
        o.x = e0 + b2f(xe[0]) * b2f(ge[0]) * sigm(pa[0]);
        o.y = e1 + b2f(xe[1]) * b2f(ge[1]) * sigm(pa[1]);
        o.z = e2 + b2f(xe[2]) * b2f(ge[2]) * sigm(pa[2]);
        o.w = e3 + b2f(xe[3]) * b2f(ge[3]) * sigm(pa[3]);
        *(float4*)&out[((size_t)b * 1290 + 290 + j) * 256 + c4] = o;
    }
}

extern "C" void kernel_launch(void* const* d_in, const int* in_sizes, int n_in,
                              void* d_out, int out_size, void* d_ws, size_t ws_size,
                              hipStream_t stream) {
    (void)in_sizes; (void)n_in; (void)out_size;
    const float* drug    = (const float*)d_in[0];
    const float* prot    = (const float*)d_in[1];
    const float* scale_d = (const float*)d_in[2];
    const float* scale_p = (const float*)d_in[3];

    char* ws = (char*)d_ws;
    size_t off = 0;
    auto alloc = [&](size_t bytes) -> void* {
        void* p = ws + off;
        off += (bytes + 255) & ~(size_t)255;
        return p;
    };
    float* pe   = (float*)alloc((size_t)1000 * 256 * 4);
    u16* e_d    = (u16*)alloc((size_t)MD * 256 * 2);
    u16* e_p    = (u16*)alloc((size_t)MP * 256 * 2);
    u16* wt     = (u16*)alloc((size_t)10 * 65536 * 2);
    u16* Qd     = (u16*)alloc((size_t)MD * 256 * 2);
    u16* Kd     = (u16*)alloc((size_t)MD * 256 * 2);
    u16* Vd     = (u16*)alloc((size_t)MD * 256 * 2);
    u16* gate_d = (u16*)alloc((size_t)MD * 256 * 2);
    u16* Kp     = (u16*)alloc((size_t)MP * 256 * 2);
    u16* Vp     = (u16*)alloc((size_t)MP * 256 * 2);
    u16* Qp     = (u16*)alloc((size_t)MP * 256 * 2);
    u16* gate_p = (u16*)alloc((size_t)MP * 256 * 2);
    u16* ctxd   = (u16*)alloc((size_t)MD * 256 * 2);
    u16* ctxp   = (u16*)alloc((size_t)MP * 256 * 2);
    float* cm   = (float*)alloc((size_t)MP * 8 * 4);
    u16* Xd     = (u16*)alloc((size_t)MD * 256 * 2);
    u16* Xp     = (u16*)alloc((size_t)MP * 256 * 2);
    if (off > ws_size) return;

    pe_kernel<<<1000, 256, 0, stream>>>(pe);

    WPtrs wp;
    const int wsrc[10] = {4, 12, 14, 25, 6, 8, 10, 27, 16, 18};
    for (int m = 0; m < 10; m++) wp.w[m] = (const float*)d_in[wsrc[m]];
    wprep_kernel<<<dim3(16, 10), 256, 0, stream>>>(wp, wt);

    eadd_kernel<<<(MD + MP) / 4, 256, 0, stream>>>(drug, prot, scale_d, scale_p, pe, e_d, e_p);

    auto W = [&](int slot) { return wt + (size_t)slot * 65536; };
    GCfg8 pc;
    pc.c[0] = { e_d, W(0), (const float*)d_in[5],  Qd,     145, 0 };
    pc.c[1] = { e_d, W(1), (const float*)d_in[13], Kd,     145, 0 };
    pc.c[2] = { e_d, W(2), (const float*)d_in[15], Vd,     145, 0 };
    pc.c[3] = { e_d, W(3), (const float*)d_in[26], gate_d, 145, 1 };
    pc.c[4] = { e_p, W(4), (const float*)d_in[7],  Kp,     500, 0 };
    pc.c[5] = { e_p, W(5), (const float*)d_in[9],  Vp,     500, 0 };
    pc.c[6] = { e_p, W(6), (const float*)d_in[11], Qp,     500, 0 };
    pc.c[7] = { e_p, W(7), (const float*)d_in[28], gate_p, 500, 1 };
    gemm_kernel<<<dim3(500, 4, 8), 256, 0, stream>>>(pc);

    attn_kernel<<<256, 512, 0, stream>>>(Qd, Kd, Vd, Kp, Vp, Qp,
                                         (const float*)d_in[20], ctxd, ctxp, cm);

    GCfg8 oc = pc;
    oc.c[0] = { ctxd, W(8), (const float*)d_in[17], Xd, 145, 0 };
    oc.c[1] = { ctxp, W(9), (const float*)d_in[19], Xp, 500, 0 };
    gemm_kernel<<<dim3(500, 4, 2), 256, 0, stream>>>(oc);

    combine_kernel<<<(MD + MP) / 4, 256, 0, stream>>>(drug, prot, scale_d, scale_p, pe,
        Xd, Xp, gate_d, gate_p, cm,
        (const float*)d_in[21], (const float*)d_in[22],
        (const float*)d_in[23], (const float*)d_in[24],
        (float*)d_out);
}